// Round 4
// baseline (380.899 us; speedup 1.0000x reference)
//
#include <hip/hip_runtime.h>
#include <hip/hip_bf16.h>
#include <math.h>

#define B_ 2
#define T_ 2048
#define E_ 1024
#define H_ 16
#define D_ 64
#define NT_ 32          // T/64 tiles
#define QSCALE 0.180336880f   // 0.125 * log2(e): folded into q so exp(S/8) = exp2(S')

typedef __attribute__((ext_vector_type(8))) short bf16x8;   // MFMA A/B frag (4 VGPRs)
typedef __attribute__((ext_vector_type(4))) float f32x4;    // MFMA C/D frag

#if __has_builtin(__builtin_amdgcn_exp2f)
#define EXP2(x) __builtin_amdgcn_exp2f(x)
#else
#define EXP2(x) exp2f(x)
#endif

__device__ __forceinline__ unsigned short f2bf(float x) {   // RNE fp32->bf16
  union { float f; unsigned u; } v; v.f = x;
  unsigned r = v.u + 0x7FFFu + ((v.u >> 16) & 1u);
  return (unsigned short)(r >> 16);
}
__device__ __forceinline__ float bf2f(unsigned short u) {
  union { float f; unsigned u; } v; v.u = ((unsigned)u) << 16; return v.f;
}
__device__ __forceinline__ unsigned pk2bf(float a, float b) {  // low=a, high=b (HW cvt_pk)
  __hip_bfloat162 h = __float22bfloat162_rn(make_float2(a, b));
  union { __hip_bfloat162 h; unsigned u; } c; c.h = h; return c.u;
}

// ---- proj-only LDS staging helpers (XOR-swizzled, global_load_lds w=16) ----
__device__ __forceinline__ void dma8(const unsigned short* g, int gstride,
                                     unsigned short* l, int lane)
{
  const int r = lane >> 3, bg = (lane & 7) ^ (r & 7);
  __builtin_amdgcn_global_load_lds(
      (const __attribute__((address_space(1))) void*)(g + (size_t)r * gstride + bg * 8),
      (__attribute__((address_space(3))) void*)l, 16, 0, 0);
}
__device__ __forceinline__ bf16x8 frag(const unsigned short* tile, int row, int g) {
  return *(const bf16x8*)(tile + row * 64 + (((g ^ row) & 7) << 3));
}

// ---------------------------------------------------------------------------
// input pre-pack: (B,T,E) fp32 -> bf16. grid 2048 x 256.
// ---------------------------------------------------------------------------
__global__ __launch_bounds__(256) void inpack_kernel(const float* __restrict__ in,
                                                     unsigned short* __restrict__ o) {
  const size_t i = ((size_t)blockIdx.x * 256 + threadIdx.x) * 8;
  float4 f0 = *(const float4*)(in + i);
  float4 f1 = *(const float4*)(in + i + 4);
  unsigned u[4] = { pk2bf(f0.x, f0.y), pk2bf(f0.z, f0.w),
                    pk2bf(f1.x, f1.y), pk2bf(f1.z, f1.w) };
  *(bf16x8*)(o + i) = *(const bf16x8*)u;
}

// ---------------------------------------------------------------------------
// weight pack: (H,E,D) fp32 -> (H,D,E) bf16. grid (E/64, H, 3) x 256.
// ---------------------------------------------------------------------------
__global__ __launch_bounds__(256) void wpack_kernel(
    const float* __restrict__ qw, const float* __restrict__ kw, const float* __restrict__ vw,
    unsigned short* __restrict__ qwt, unsigned short* __restrict__ kwt,
    unsigned short* __restrict__ vwt)
{
  __shared__ float s[64][65];
  const int tid = threadIdx.x;
  const int e0 = blockIdx.x * 64, h = blockIdx.y, z = blockIdx.z;
  const float* w = (z == 0) ? qw : (z == 1) ? kw : vw;
  unsigned short* o = (z == 0) ? qwt : (z == 1) ? kwt : vwt;
  {
    const int r = tid >> 2;
    #pragma unroll
    for (int p = 0; p < 4; ++p) {
      const int c = (tid & 3) * 4 + p * 16;
      float4 f = *(const float4*)(w + ((size_t)(h * E_ + e0 + r)) * D_ + c);
      s[r][c] = f.x; s[r][c+1] = f.y; s[r][c+2] = f.z; s[r][c+3] = f.w;
    }
  }
  __syncthreads();
  {
    const int d = tid >> 2, ec = (tid & 3) * 16;
    unsigned short tmp[16];
    #pragma unroll
    for (int j = 0; j < 16; ++j) tmp[j] = f2bf(s[ec + j][d]);
    unsigned short* dst = o + ((size_t)(h * D_ + d)) * E_ + e0 + ec;
    *(bf16x8*)(dst)     = *(const bf16x8*)&tmp[0];
    *(bf16x8*)(dst + 8) = *(const bf16x8*)&tmp[8];
  }
}

// ---------------------------------------------------------------------------
// QKV projection (m97-style, double-buffered global_load_lds). grid
// (T/128, H, B) = 512 x 256. Q output pre-scaled by QSCALE.
// ---------------------------------------------------------------------------
__global__ __launch_bounds__(256) void proj_kernel(
    const unsigned short* __restrict__ in16,
    const unsigned short* __restrict__ qwt, const unsigned short* __restrict__ kwt,
    const unsigned short* __restrict__ vwt,
    const float* __restrict__ qb, const float* __restrict__ kb, const float* __restrict__ vb,
    unsigned short* __restrict__ qo, unsigned short* __restrict__ ko,
    unsigned short* __restrict__ vo)
{
  __shared__ __align__(16) unsigned short in_s[2][128 * 64];   // 32 KB
  __shared__ __align__(16) unsigned short w_s[2][3][64 * 64];  // 48 KB
  const int tid = threadIdx.x;
  const int lane = tid & 63, wv = tid >> 6;
  const int l15 = lane & 15, quad = lane >> 4;
  const int t0 = blockIdx.x * 128, h = blockIdx.y, b = blockIdx.z;
  const unsigned short* wts[3] = { qwt, kwt, vwt };

  f32x4 acc[3][2][4];
  #pragma unroll
  for (int x = 0; x < 3; ++x)
    #pragma unroll
    for (int s = 0; s < 2; ++s)
      #pragma unroll
      for (int nb = 0; nb < 4; ++nb) acc[x][s][nb] = (f32x4){0.f, 0.f, 0.f, 0.f};

#define PROJ_STAGE(e0_, bi_)                                                      \
  {                                                                               \
    const unsigned short* gin = in16 + ((size_t)(b * T_ + t0)) * E_ + (e0_);      \
    _Pragma("unroll")                                                             \
    for (int p = 0; p < 4; ++p) {                                                 \
      const int br = wv * 32 + p * 8;                                             \
      dma8(gin + (size_t)br * E_, E_, &in_s[bi_][br * 64], lane);                 \
    }                                                                             \
    _Pragma("unroll")                                                             \
    for (int j = 0; j < 6; ++j) {                                                 \
      const int idx = wv * 6 + j;                                                 \
      const int x = idx >> 3, br = (idx & 7) * 8;                                 \
      dma8(wts[x] + ((size_t)(h * D_ + br)) * E_ + (e0_), E_,                     \
           &w_s[bi_][x][br * 64], lane);                                          \
    }                                                                             \
  }

  PROJ_STAGE(0, 0);
  __syncthreads();
  for (int e = 0; e < 16; ++e) {
    const int bi = e & 1;
    if (e < 15) PROJ_STAGE((e + 1) * 64, bi ^ 1);
    const unsigned short* is = in_s[bi];
    #pragma unroll
    for (int kk = 0; kk < 2; ++kk) {
      const int g0 = kk * 4 + quad;
      bf16x8 a0 = frag(is, wv * 32 + l15, g0);
      bf16x8 a1 = frag(is, wv * 32 + 16 + l15, g0);
      #pragma unroll
      for (int x = 0; x < 3; ++x) {
        const unsigned short* ws = w_s[bi][x];
        #pragma unroll
        for (int nb = 0; nb < 4; ++nb) {
          bf16x8 bfr = frag(ws, nb * 16 + l15, g0);
          acc[x][0][nb] = __builtin_amdgcn_mfma_f32_16x16x32_bf16(a0, bfr, acc[x][0][nb], 0, 0, 0);
          acc[x][1][nb] = __builtin_amdgcn_mfma_f32_16x16x32_bf16(a1, bfr, acc[x][1][nb], 0, 0, 0);
        }
      }
    }
    __syncthreads();
  }
#undef PROJ_STAGE

  const size_t obase = (size_t)(b * H_ + h) * T_;
  unsigned short* outs[3] = { qo, ko, vo };
  const float* biasp[3] = { qb, kb, vb };
  #pragma unroll
  for (int x = 0; x < 3; ++x) {
    const float scl = (x == 0) ? QSCALE : 1.0f;
    #pragma unroll
    for (int nb = 0; nb < 4; ++nb) {
      const int d = nb * 16 + l15;
      const float bvv = biasp[x][h * D_ + d];
      #pragma unroll
      for (int s = 0; s < 2; ++s)
        #pragma unroll
        for (int r = 0; r < 4; ++r) {
          const int t = t0 + wv * 32 + s * 16 + quad * 4 + r;
          outs[x][(obase + t) * D_ + d] = f2bf((acc[x][s][nb][r] + bvv) * scl);
        }
    }
  }
}

// ---------------------------------------------------------------------------
// Column softmax sums + V pre-scale/transpose. grid (32, H, B) = 1024 blocks.
// BARRIER-FREE main loop: K B-frags reg-resident, Q A-frags loaded directly
// global->VGPR (coalesced: 16 full rows per wave-instr). Heavy tiles (sa=0)
// dispatch first. Epilogue: vt[bh][d][t] = v[bh][t][d] / l[t].
// ---------------------------------------------------------------------------
__global__ __launch_bounds__(256) void stats_kernel(
    const unsigned short* __restrict__ q, const unsigned short* __restrict__ k,
    const unsigned short* __restrict__ v, unsigned short* __restrict__ vt)
{
  __shared__ float red[4][64];
  __shared__ float rl_sh[64];
  const int tid = threadIdx.x;
  const int lane = tid & 63, wv = tid >> 6;
  const int l15 = lane & 15, quad = lane >> 4;
  const int sa = blockIdx.x;                     // sa=0 heaviest, dispatched first
  const int bh = blockIdx.z * H_ + blockIdx.y;
  const int s0 = sa * 64;
  const unsigned short* kbase = k + (size_t)bh * T_ * 64;
  const unsigned short* qbase = q + (size_t)bh * T_ * 64;

  bf16x8 kf[4][2];                               // reg-resident K B-frags
  #pragma unroll
  for (int nb = 0; nb < 4; ++nb)
    #pragma unroll
    for (int kk = 0; kk < 2; ++kk)
      kf[nb][kk] = *(const bf16x8*)(kbase + (size_t)(s0 + nb * 16 + l15) * 64 + kk * 32 + quad * 8);

  float lsum[4] = {0.f, 0.f, 0.f, 0.f};

  for (int tt = sa; tt < NT_; ++tt) {
    const unsigned short* qrow = qbase + (size_t)(tt * 64 + wv * 16 + l15) * 64;
    bf16x8 a0 = *(const bf16x8*)(qrow + quad * 8);
    bf16x8 a1 = *(const bf16x8*)(qrow + 32 + quad * 8);
    f32x4 sacc[4];
    #pragma unroll
    for (int nb = 0; nb < 4; ++nb) sacc[nb] = (f32x4){0.f, 0.f, 0.f, 0.f};
    #pragma unroll
    for (int nb = 0; nb < 4; ++nb) {
      sacc[nb] = __builtin_amdgcn_mfma_f32_16x16x32_bf16(a0, kf[nb][0], sacc[nb], 0, 0, 0);
      sacc[nb] = __builtin_amdgcn_mfma_f32_16x16x32_bf16(a1, kf[nb][1], sacc[nb], 0, 0, 0);
    }
    if (tt == sa) {                              // diagonal tile: causal mask
      const int tbase = tt * 64 + wv * 16 + quad * 4;
      #pragma unroll
      for (int nb = 0; nb < 4; ++nb) {
        const int s = s0 + nb * 16 + l15;
        #pragma unroll
        for (int r = 0; r < 4; ++r)
          lsum[nb] += (tbase + r >= s) ? EXP2(sacc[nb][r]) : 0.f;
      }
    } else {                                     // fully unmasked
      #pragma unroll
      for (int nb = 0; nb < 4; ++nb)
        #pragma unroll
        for (int r = 0; r < 4; ++r) lsum[nb] += EXP2(sacc[nb][r]);
    }
  }
  #pragma unroll
  for (int nb = 0; nb < 4; ++nb) {
    lsum[nb] += __shfl_xor(lsum[nb], 16);
    lsum[nb] += __shfl_xor(lsum[nb], 32);
  }
  if (lane < 16) {
    #pragma unroll
    for (int nb = 0; nb < 4; ++nb) red[wv][nb * 16 + lane] = lsum[nb];
  }
  __syncthreads();
  if (tid < 64)
    rl_sh[tid] = 1.0f / (red[0][tid] + red[1][tid] + red[2][tid] + red[3][tid]);
  __syncthreads();
  // vt[bh][d][t] = v[bh][t][d] * rl[t]
  {
    const int sI = tid >> 2, c = (tid & 3) * 16;
    const unsigned short* gv = v + ((size_t)(bh * T_ + s0 + sI)) * 64 + c;
    bf16x8 v0 = *(const bf16x8*)gv;
    bf16x8 v1 = *(const bf16x8*)(gv + 8);
    const float r = rl_sh[sI];
    #pragma unroll
    for (int j = 0; j < 8; ++j)
      vt[((size_t)(bh * D_ + c + j)) * T_ + s0 + sI] = f2bf(bf2f((unsigned short)v0[j]) * r);
    #pragma unroll
    for (int j = 0; j < 8; ++j)
      vt[((size_t)(bh * D_ + c + 8 + j)) * T_ + s0 + sI] = f2bf(bf2f((unsigned short)v1[j]) * r);
  }
}

// ---------------------------------------------------------------------------
// Output. grid (32, H, B) = 1024 blocks, BARRIER-FREE. Wave owns 16 t-cols:
// S^T = K.Q^T (A=K direct-global, B=Q reg-resident), U=exp2(S) -> wave-private
// LDS row (layout switch), O += U.Vt (B=Vt direct-global). Heavy (jt=31)
// blocks dispatch first.
// ---------------------------------------------------------------------------
__global__ __launch_bounds__(256) void out_kernel(
    const unsigned short* __restrict__ q, const unsigned short* __restrict__ k,
    const unsigned short* __restrict__ vt, float* __restrict__ out)
{
  __shared__ __align__(16) unsigned short u_s[4][16][72];   // [wave][t][s] 9.2 KB
  const int tid = threadIdx.x;
  const int lane = tid & 63, wv = tid >> 6;
  const int l15 = lane & 15, quad = lane >> 4;
  const int jt = 31 - blockIdx.x;                // heavy-first
  const int bh = blockIdx.z * H_ + blockIdx.y;
  const int t0 = jt * 64;
  const unsigned short* kbase = k + (size_t)bh * T_ * 64;
  const unsigned short* vbase = vt + (size_t)bh * D_ * T_;

  const unsigned short* qrow = q + (size_t)(bh * T_ + t0 + wv * 16 + l15) * 64;
  bf16x8 qf0 = *(const bf16x8*)(qrow + quad * 8);          // reg-resident Q B-frags
  bf16x8 qf1 = *(const bf16x8*)(qrow + 32 + quad * 8);

  f32x4 oacc[4];
  #pragma unroll
  for (int nb = 0; nb < 4; ++nb) oacc[nb] = (f32x4){0.f, 0.f, 0.f, 0.f};

  unsigned short* urow = &u_s[wv][l15][0];       // this lane's U row (t = l15)
  const int tcol = t0 + wv * 16 + l15;

  for (int st = 0; st <= jt; ++st) {
    const int s0 = st * 64;
    f32x4 sacc[4];
    #pragma unroll
    for (int mb = 0; mb < 4; ++mb) sacc[mb] = (f32x4){0.f, 0.f, 0.f, 0.f};
    #pragma unroll
    for (int mb = 0; mb < 4; ++mb) {
      const unsigned short* krow = kbase + (size_t)(s0 + mb * 16 + l15) * 64;
      bf16x8 ka0 = *(const bf16x8*)(krow + quad * 8);
      bf16x8 ka1 = *(const bf16x8*)(krow + 32 + quad * 8);
      sacc[mb] = __builtin_amdgcn_mfma_f32_16x16x32_bf16(ka0, qf0, sacc[mb], 0, 0, 0);
      sacc[mb] = __builtin_amdgcn_mfma_f32_16x16x32_bf16(ka1, qf1, sacc[mb], 0, 0, 0);
    }
    if (st == jt) {                              // diagonal tile: causal mask
      #pragma unroll
      for (int mb = 0; mb < 4; ++mb) {
        const int sbase = s0 + mb * 16 + quad * 4;
        float uu[4];
        #pragma unroll
        for (int r = 0; r < 4; ++r)
          uu[r] = (tcol >= sbase + r) ? EXP2(sacc[mb][r]) : 0.f;
        *(uint2*)(urow + mb * 16 + quad * 4) =
            make_uint2(pk2bf(uu[0], uu[1]), pk2bf(uu[2], uu[3]));
      }
    } else {                                     // unmasked
      #pragma unroll
      for (int mb = 0; mb < 4; ++mb) {
        float uu[4];
        #pragma unroll
        for (int r = 0; r < 4; ++r) uu[r] = EXP2(sacc[mb][r]);
        *(uint2*)(urow + mb * 16 + quad * 4) =
            make_uint2(pk2bf(uu[0], uu[1]), pk2bf(uu[2], uu[3]));
      }
    }
    // O += U @ Vt' — same-wave LDS dep only (no barrier anywhere)
    #pragma unroll
    for (int kk = 0; kk < 2; ++kk) {
      bf16x8 ua = *(const bf16x8*)(urow + kk * 32 + quad * 8);
      #pragma unroll
      for (int nb = 0; nb < 4; ++nb) {
        bf16x8 vb = *(const bf16x8*)(vbase + (size_t)(nb * 16 + l15) * T_ + s0 + kk * 32 + quad * 8);
        oacc[nb] = __builtin_amdgcn_mfma_f32_16x16x32_bf16(ua, vb, oacc[nb], 0, 0, 0);
      }
    }
  }
  // write (B, T, H*D) fp32
  #pragma unroll
  for (int nb = 0; nb < 4; ++nb) {
    const int d = nb * 16 + l15;
    #pragma unroll
    for (int r = 0; r < 4; ++r) {
      const int t = t0 + wv * 16 + quad * 4 + r;
      out[((size_t)(blockIdx.z * T_ + t)) * (H_ * D_) + blockIdx.y * D_ + d] = oacc[nb][r];
    }
  }
}

extern "C" void kernel_launch(void* const* d_in, const int* in_sizes, int n_in,
                              void* d_out, int out_size, void* d_ws, size_t ws_size,
                              hipStream_t stream) {
  const float* in = (const float*)d_in[0];
  const float* kw = (const float*)d_in[1];
  const float* kb = (const float*)d_in[2];
  const float* qw = (const float*)d_in[3];
  const float* qb = (const float*)d_in[4];
  const float* vw = (const float*)d_in[5];
  const float* vb = (const float*)d_in[6];
  float* out = (float*)d_out;

  // ws (bf16): in16 | qwt|kwt|vwt (H,D,E) | q16|k16|v16 (B,H,T,D) | vt (B,H,D,T)
  unsigned short* p = (unsigned short*)d_ws;
  const size_t inz = (size_t)B_ * T_ * E_;
  const size_t wz  = (size_t)H_ * D_ * E_;
  const size_t qz  = (size_t)B_ * H_ * T_ * D_;
  unsigned short* in16 = p;            p += inz;
  unsigned short* qwt  = p;            p += wz;
  unsigned short* kwt  = p;            p += wz;
  unsigned short* vwt  = p;            p += wz;
  unsigned short* q16  = p;            p += qz;
  unsigned short* k16  = p;            p += qz;
  unsigned short* v16  = p;            p += qz;
  unsigned short* vtb  = p;            p += qz;

  dim3 blk(256);
  inpack_kernel<<<dim3(inz / 2048), blk, 0, stream>>>(in, in16);
  wpack_kernel <<<dim3(E_ / 64, H_, 3), blk, 0, stream>>>(qw, kw, vw, qwt, kwt, vwt);
  proj_kernel  <<<dim3(T_ / 128, H_, B_), blk, 0, stream>>>(in16, qwt, kwt, vwt,
                                                            qb, kb, vb, q16, k16, v16);
  stats_kernel <<<dim3(NT_, H_, B_), blk, 0, stream>>>(q16, k16, v16, vtb);
  out_kernel   <<<dim3(NT_, H_, B_), blk, 0, stream>>>(q16, k16, vtb, out);
}

// Round 5
// 209.137 us; speedup vs baseline: 1.8213x; 1.8213x over previous
//
#include <hip/hip_runtime.h>
#include <hip/hip_bf16.h>
#include <math.h>

#define B_ 2
#define T_ 2048
#define E_ 1024
#define H_ 16
#define D_ 64
#define NT_ 32          // T/64 tiles
#define QSCALE 0.180336880f   // 0.125 * log2(e): folded into q so exp(S/8) = exp2(S')

typedef __attribute__((ext_vector_type(8))) short bf16x8;   // MFMA A/B frag (4 VGPRs)
typedef __attribute__((ext_vector_type(4))) float f32x4;    // MFMA C/D frag

#if __has_builtin(__builtin_amdgcn_exp2f)
#define EXP2(x) __builtin_amdgcn_exp2f(x)
#else
#define EXP2(x) exp2f(x)
#endif

__device__ __forceinline__ unsigned short f2bf(float x) {   // RNE fp32->bf16
  union { float f; unsigned u; } v; v.f = x;
  unsigned r = v.u + 0x7FFFu + ((v.u >> 16) & 1u);
  return (unsigned short)(r >> 16);
}
__device__ __forceinline__ unsigned pk2bf(float a, float b) {  // low=a, high=b (HW cvt_pk)
  __hip_bfloat162 h = __float22bfloat162_rn(make_float2(a, b));
  union { __hip_bfloat162 h; unsigned u; } c; c.h = h; return c.u;
}

// Async global->LDS: one wave-instr stages 8 rows x 64 bf16 (8 blocks of 16B),
// XOR-swizzled: LDS slot (row, bs) holds global block bs ^ (row&7).
__device__ __forceinline__ void dma8(const unsigned short* g, int gstride,
                                     unsigned short* l, int lane)
{
  const int r = lane >> 3, bg = (lane & 7) ^ (r & 7);
  __builtin_amdgcn_global_load_lds(
      (const __attribute__((address_space(1))) void*)(g + (size_t)r * gstride + bg * 8),
      (__attribute__((address_space(3))) void*)l, 16, 0, 0);
}
__device__ __forceinline__ bf16x8 frag(const unsigned short* tile, int row, int g) {
  return *(const bf16x8*)(tile + row * 64 + (((g ^ row) & 7) << 3));
}

// ---------------------------------------------------------------------------
// input pre-pack: (B,T,E) fp32 -> bf16. grid 2048 x 256.
// ---------------------------------------------------------------------------
__global__ __launch_bounds__(256) void inpack_kernel(const float* __restrict__ in,
                                                     unsigned short* __restrict__ o) {
  const size_t i = ((size_t)blockIdx.x * 256 + threadIdx.x) * 8;
  float4 f0 = *(const float4*)(in + i);
  float4 f1 = *(const float4*)(in + i + 4);
  unsigned u[4] = { pk2bf(f0.x, f0.y), pk2bf(f0.z, f0.w),
                    pk2bf(f1.x, f1.y), pk2bf(f1.z, f1.w) };
  *(bf16x8*)(o + i) = *(const bf16x8*)u;
}

// ---------------------------------------------------------------------------
// weight pack: (H,E,D) fp32 -> (H,D,E) bf16. grid (E/64, H, 3) x 256.
// ---------------------------------------------------------------------------
__global__ __launch_bounds__(256) void wpack_kernel(
    const float* __restrict__ qw, const float* __restrict__ kw, const float* __restrict__ vw,
    unsigned short* __restrict__ qwt, unsigned short* __restrict__ kwt,
    unsigned short* __restrict__ vwt)
{
  __shared__ float s[64][65];
  const int tid = threadIdx.x;
  const int e0 = blockIdx.x * 64, h = blockIdx.y, z = blockIdx.z;
  const float* w = (z == 0) ? qw : (z == 1) ? kw : vw;
  unsigned short* o = (z == 0) ? qwt : (z == 1) ? kwt : vwt;
  {
    const int r = tid >> 2;
    #pragma unroll
    for (int p = 0; p < 4; ++p) {
      const int c = (tid & 3) * 4 + p * 16;
      float4 f = *(const float4*)(w + ((size_t)(h * E_ + e0 + r)) * D_ + c);
      s[r][c] = f.x; s[r][c+1] = f.y; s[r][c+2] = f.z; s[r][c+3] = f.w;
    }
  }
  __syncthreads();
  {
    const int d = tid >> 2, ec = (tid & 3) * 16;
    unsigned short tmp[16];
    #pragma unroll
    for (int j = 0; j < 16; ++j) tmp[j] = f2bf(s[ec + j][d]);
    unsigned short* dst = o + ((size_t)(h * D_ + d)) * E_ + e0 + ec;
    *(bf16x8*)(dst)     = *(const bf16x8*)&tmp[0];
    *(bf16x8*)(dst + 8) = *(const bf16x8*)&tmp[8];
  }
}

// ---------------------------------------------------------------------------
// QKV projection (double-buffered global_load_lds). grid (T/128, H, B) = 512.
// Writes q16 (pre-scaled by QSCALE), k16 (row-major), and V TRANSPOSED
// (vt[bh][d][t]) directly from accumulator regs.
// ---------------------------------------------------------------------------
__global__ __launch_bounds__(256) void proj_kernel(
    const unsigned short* __restrict__ in16,
    const unsigned short* __restrict__ qwt, const unsigned short* __restrict__ kwt,
    const unsigned short* __restrict__ vwt,
    const float* __restrict__ qb, const float* __restrict__ kb, const float* __restrict__ vb,
    unsigned short* __restrict__ qo, unsigned short* __restrict__ ko,
    unsigned short* __restrict__ vt)
{
  __shared__ __align__(16) unsigned short in_s[2][128 * 64];   // 32 KB
  __shared__ __align__(16) unsigned short w_s[2][3][64 * 64];  // 48 KB
  const int tid = threadIdx.x;
  const int lane = tid & 63, wv = tid >> 6;
  const int l15 = lane & 15, quad = lane >> 4;
  const int t0 = blockIdx.x * 128, h = blockIdx.y, b = blockIdx.z;
  const int bh = b * H_ + h;
  const unsigned short* wts[3] = { qwt, kwt, vwt };

  f32x4 acc[3][2][4];
  #pragma unroll
  for (int x = 0; x < 3; ++x)
    #pragma unroll
    for (int s = 0; s < 2; ++s)
      #pragma unroll
      for (int nb = 0; nb < 4; ++nb) acc[x][s][nb] = (f32x4){0.f, 0.f, 0.f, 0.f};

#define PROJ_STAGE(e0_, bi_)                                                      \
  {                                                                               \
    const unsigned short* gin = in16 + ((size_t)(b * T_ + t0)) * E_ + (e0_);      \
    _Pragma("unroll")                                                             \
    for (int p = 0; p < 4; ++p) {                                                 \
      const int br = wv * 32 + p * 8;                                             \
      dma8(gin + (size_t)br * E_, E_, &in_s[bi_][br * 64], lane);                 \
    }                                                                             \
    _Pragma("unroll")                                                             \
    for (int j = 0; j < 6; ++j) {                                                 \
      const int idx = wv * 6 + j;                                                 \
      const int x = idx >> 3, br = (idx & 7) * 8;                                 \
      dma8(wts[x] + ((size_t)(h * D_ + br)) * E_ + (e0_), E_,                     \
           &w_s[bi_][x][br * 64], lane);                                          \
    }                                                                             \
  }

  PROJ_STAGE(0, 0);
  __syncthreads();
  for (int e = 0; e < 16; ++e) {
    const int bi = e & 1;
    if (e < 15) PROJ_STAGE((e + 1) * 64, bi ^ 1);
    const unsigned short* is = in_s[bi];
    #pragma unroll
    for (int kk = 0; kk < 2; ++kk) {
      const int g0 = kk * 4 + quad;
      bf16x8 a0 = frag(is, wv * 32 + l15, g0);
      bf16x8 a1 = frag(is, wv * 32 + 16 + l15, g0);
      #pragma unroll
      for (int x = 0; x < 3; ++x) {
        const unsigned short* ws = w_s[bi][x];
        #pragma unroll
        for (int nb = 0; nb < 4; ++nb) {
          bf16x8 bfr = frag(ws, nb * 16 + l15, g0);
          acc[x][0][nb] = __builtin_amdgcn_mfma_f32_16x16x32_bf16(a0, bfr, acc[x][0][nb], 0, 0, 0);
          acc[x][1][nb] = __builtin_amdgcn_mfma_f32_16x16x32_bf16(a1, bfr, acc[x][1][nb], 0, 0, 0);
        }
      }
    }
    __syncthreads();
  }
#undef PROJ_STAGE

  const size_t obase = (size_t)bh * T_;
  // q (scaled) and k: row-major [t][d]
  #pragma unroll
  for (int x = 0; x < 2; ++x) {
    const float scl = (x == 0) ? QSCALE : 1.0f;
    const float* bias = (x == 0) ? qb : kb;
    unsigned short* outp = (x == 0) ? qo : ko;
    #pragma unroll
    for (int nb = 0; nb < 4; ++nb) {
      const int d = nb * 16 + l15;
      const float bvv = bias[h * D_ + d];
      #pragma unroll
      for (int s = 0; s < 2; ++s)
        #pragma unroll
        for (int r = 0; r < 4; ++r) {
          const int t = t0 + wv * 32 + s * 16 + quad * 4 + r;
          outp[(obase + t) * D_ + d] = f2bf((acc[x][s][nb][r] + bvv) * scl);
        }
    }
  }
  // v: transposed [d][t] — 4 t-consecutive values pack into one 8B store
  #pragma unroll
  for (int nb = 0; nb < 4; ++nb) {
    const int d = nb * 16 + l15;
    const float bvv = vb[h * D_ + d];
    #pragma unroll
    for (int s = 0; s < 2; ++s) {
      const int t = t0 + wv * 32 + s * 16 + quad * 4;
      unsigned short pk[4];
      #pragma unroll
      for (int r = 0; r < 4; ++r) pk[r] = f2bf(acc[2][s][nb][r] + bvv);
      *(ushort4*)(vt + ((size_t)(bh * D_ + d)) * T_ + t) = *(const ushort4*)pk;
    }
  }
}

// ---------------------------------------------------------------------------
// Column softmax partial sums (softmax over QUERY axis). grid (64, H, B) =
// 2048 blocks (8/CU, all resident). Block = (s-tile sa, t-parity p); iterates
// tt = sa..31 with tt%2==p; K B-frags reg-resident (one-time global loads),
// Q dbuf via dma8. Partial column sums atomicAdd'd into l (zero-init).
// ---------------------------------------------------------------------------
__global__ __launch_bounds__(256) void stats_kernel(
    const unsigned short* __restrict__ q, const unsigned short* __restrict__ k,
    float* __restrict__ l)
{
  __shared__ __align__(16) unsigned short q_s[2][64 * 64];   // 16 KB
  __shared__ float red[4][64];
  const int tid = threadIdx.x;
  const int lane = tid & 63, wv = tid >> 6;
  const int l15 = lane & 15, quad = lane >> 4;
  const int sa = blockIdx.x >> 1, p = blockIdx.x & 1;   // sa=0 heaviest, first
  const int tt0 = sa + ((sa ^ p) & 1);
  if (tt0 >= NT_) return;
  const int bh = blockIdx.z * H_ + blockIdx.y;
  const int s0 = sa * 64;
  const unsigned short* qbase = q + (size_t)bh * T_ * 64;

  bf16x8 kf[4][2];                               // reg-resident K B-frags (one-time)
  #pragma unroll
  for (int nb = 0; nb < 4; ++nb)
    #pragma unroll
    for (int kk = 0; kk < 2; ++kk)
      kf[nb][kk] = *(const bf16x8*)(k + ((size_t)(bh * T_ + s0 + nb * 16 + l15)) * 64
                                      + kk * 32 + quad * 8);

  #pragma unroll
  for (int pp = 0; pp < 2; ++pp) {
    const int br = wv * 16 + pp * 8;
    dma8(qbase + (size_t)(tt0 * 64 + br) * 64, 64, &q_s[0][br * 64], lane);
  }
  __syncthreads();

  float lsum[4] = {0.f, 0.f, 0.f, 0.f};

  for (int tt = tt0, i = 0; tt < NT_; tt += 2, ++i) {
    const int bi = i & 1;
    if (tt + 2 < NT_) {
      #pragma unroll
      for (int pp = 0; pp < 2; ++pp) {
        const int br = wv * 16 + pp * 8;
        dma8(qbase + (size_t)((tt + 2) * 64 + br) * 64, 64, &q_s[bi ^ 1][br * 64], lane);
      }
    }
    bf16x8 a0 = frag(q_s[bi], wv * 16 + l15, quad);
    bf16x8 a1 = frag(q_s[bi], wv * 16 + l15, 4 + quad);
    f32x4 sacc[4];
    #pragma unroll
    for (int nb = 0; nb < 4; ++nb) sacc[nb] = (f32x4){0.f, 0.f, 0.f, 0.f};
    #pragma unroll
    for (int nb = 0; nb < 4; ++nb) {
      sacc[nb] = __builtin_amdgcn_mfma_f32_16x16x32_bf16(a0, kf[nb][0], sacc[nb], 0, 0, 0);
      sacc[nb] = __builtin_amdgcn_mfma_f32_16x16x32_bf16(a1, kf[nb][1], sacc[nb], 0, 0, 0);
    }
    if (tt == sa) {                              // diagonal tile: causal mask
      const int tbase = tt * 64 + wv * 16 + quad * 4;
      #pragma unroll
      for (int nb = 0; nb < 4; ++nb) {
        const int s = s0 + nb * 16 + l15;
        #pragma unroll
        for (int r = 0; r < 4; ++r)
          lsum[nb] += (tbase + r >= s) ? EXP2(sacc[nb][r]) : 0.f;
      }
    } else {
      #pragma unroll
      for (int nb = 0; nb < 4; ++nb)
        #pragma unroll
        for (int r = 0; r < 4; ++r) lsum[nb] += EXP2(sacc[nb][r]);
    }
    __syncthreads();
  }
  #pragma unroll
  for (int nb = 0; nb < 4; ++nb) {
    lsum[nb] += __shfl_xor(lsum[nb], 16);
    lsum[nb] += __shfl_xor(lsum[nb], 32);
  }
  if (lane < 16) {
    #pragma unroll
    for (int nb = 0; nb < 4; ++nb) red[wv][nb * 16 + lane] = lsum[nb];
  }
  __syncthreads();
  if (tid < 64)
    unsafeAtomicAdd(&l[(size_t)bh * T_ + s0 + tid],
                    red[0][tid] + red[1][tid] + red[2][tid] + red[3][tid]);
}

// ---------------------------------------------------------------------------
// Output. grid (64, H, B) = 2048 blocks (3/CU by LDS). Block = (t-tile jt,
// s-parity p): st = p, p+2, ... <= jt. LDS-staged dbuf K/Vt via dma8 (the
// measured-good structure); Q frags one-time direct-global; rl = 1/l dbuf'd
// in LDS; U = exp2(S^T)*rl through wave-private LDS; partial O atomicAdd'd
// into zero-initialized out. jt descending (heavy-first).
// ---------------------------------------------------------------------------
__global__ __launch_bounds__(256) void out_kernel(
    const unsigned short* __restrict__ q, const unsigned short* __restrict__ k,
    const unsigned short* __restrict__ vt, const float* __restrict__ l,
    float* __restrict__ out)
{
  __shared__ __align__(16) unsigned short k_s[2][64 * 64];    // 16 KB
  __shared__ __align__(16) unsigned short vt_s[2][64 * 64];   // 16 KB
  __shared__ __align__(16) unsigned short u_s[4][16][72];     // 9.2 KB wave-private
  __shared__ float rl_sh[2][64];
  const int tid = threadIdx.x;
  const int lane = tid & 63, wv = tid >> 6;
  const int l15 = lane & 15, quad = lane >> 4;
  const int jt = 31 - (blockIdx.x >> 1), p = blockIdx.x & 1;  // heavy-first
  if (jt < p) return;
  const int n_u = (jt - p) / 2 + 1;
  const int bh = blockIdx.z * H_ + blockIdx.y;
  const int t0 = jt * 64;
  const unsigned short* kbase = k + (size_t)bh * T_ * 64;
  const unsigned short* vbase = vt + (size_t)bh * D_ * T_;
  const float* lbase = l + (size_t)bh * T_;

  // one-time Q B-frags (direct global)
  const unsigned short* qrow = q + (size_t)(bh * T_ + t0 + wv * 16 + l15) * 64;
  bf16x8 qf0 = *(const bf16x8*)(qrow + quad * 8);
  bf16x8 qf1 = *(const bf16x8*)(qrow + 32 + quad * 8);

  // stage unit 0
  {
    const int s0 = p * 64;
    #pragma unroll
    for (int pp = 0; pp < 2; ++pp) {
      const int br = wv * 16 + pp * 8;
      dma8(kbase + (size_t)(s0 + br) * 64, 64, &k_s[0][br * 64], lane);
      dma8(vbase + (size_t)br * T_ + s0, T_, &vt_s[0][br * 64], lane);
    }
    if (tid < 64) rl_sh[0][tid] = 1.0f / lbase[s0 + tid];
  }
  __syncthreads();

  f32x4 oacc[4];
  #pragma unroll
  for (int nb = 0; nb < 4; ++nb) oacc[nb] = (f32x4){0.f, 0.f, 0.f, 0.f};

  unsigned short* urow = &u_s[wv][l15][0];
  const int tcol = t0 + wv * 16 + l15;

  for (int i = 0; i < n_u; ++i) {
    const int st = p + 2 * i;
    const int s0 = st * 64;
    const int bi = i & 1;
    if (i + 1 < n_u) {                           // prefetch next unit
      const int s1 = s0 + 128;
      #pragma unroll
      for (int pp = 0; pp < 2; ++pp) {
        const int br = wv * 16 + pp * 8;
        dma8(kbase + (size_t)(s1 + br) * 64, 64, &k_s[bi ^ 1][br * 64], lane);
        dma8(vbase + (size_t)br * T_ + s1, T_, &vt_s[bi ^ 1][br * 64], lane);
      }
      if (tid < 64) rl_sh[bi ^ 1][tid] = 1.0f / lbase[s1 + tid];
    }
    // S^T tile: A = K rows (s), B = Q (reg)
    const unsigned short* ks = k_s[bi];
    f32x4 sacc[4];
    #pragma unroll
    for (int mb = 0; mb < 4; ++mb) sacc[mb] = (f32x4){0.f, 0.f, 0.f, 0.f};
    #pragma unroll
    for (int mb = 0; mb < 4; ++mb) {
      bf16x8 ka0 = frag(ks, mb * 16 + l15, quad);
      bf16x8 ka1 = frag(ks, mb * 16 + l15, 4 + quad);
      sacc[mb] = __builtin_amdgcn_mfma_f32_16x16x32_bf16(ka0, qf0, sacc[mb], 0, 0, 0);
      sacc[mb] = __builtin_amdgcn_mfma_f32_16x16x32_bf16(ka1, qf1, sacc[mb], 0, 0, 0);
    }
    // U = exp2(S^T) * rl[s], masked on diagonal tile; write wave-private row
    const float* rlb = rl_sh[bi];
    if (st == jt) {
      #pragma unroll
      for (int mb = 0; mb < 4; ++mb) {
        const int sbase = s0 + mb * 16 + quad * 4;
        float4 rv = *(const float4*)&rlb[mb * 16 + quad * 4];
        float uu[4] = { EXP2(sacc[mb][0]) * rv.x, EXP2(sacc[mb][1]) * rv.y,
                        EXP2(sacc[mb][2]) * rv.z, EXP2(sacc[mb][3]) * rv.w };
        #pragma unroll
        for (int r = 0; r < 4; ++r) if (tcol < sbase + r) uu[r] = 0.f;
        *(uint2*)(urow + mb * 16 + quad * 4) =
            make_uint2(pk2bf(uu[0], uu[1]), pk2bf(uu[2], uu[3]));
      }
    } else {
      #pragma unroll
      for (int mb = 0; mb < 4; ++mb) {
        float4 rv = *(const float4*)&rlb[mb * 16 + quad * 4];
        float uu[4] = { EXP2(sacc[mb][0]) * rv.x, EXP2(sacc[mb][1]) * rv.y,
                        EXP2(sacc[mb][2]) * rv.z, EXP2(sacc[mb][3]) * rv.w };
        *(uint2*)(urow + mb * 16 + quad * 4) =
            make_uint2(pk2bf(uu[0], uu[1]), pk2bf(uu[2], uu[3]));
      }
    }
    // O += U @ Vt' — same-wave LDS dependency only
    const unsigned short* vs = vt_s[bi];
    #pragma unroll
    for (int kk = 0; kk < 2; ++kk) {
      bf16x8 ua = *(const bf16x8*)(urow + kk * 32 + quad * 8);
      #pragma unroll
      for (int nb = 0; nb < 4; ++nb)
        oacc[nb] = __builtin_amdgcn_mfma_f32_16x16x32_bf16(
            ua, frag(vs, nb * 16 + l15, kk * 4 + quad), oacc[nb], 0, 0, 0);
    }
    __syncthreads();
  }
  // accumulate partial O into zero-initialized out (B, T, H*D) fp32
  #pragma unroll
  for (int nb = 0; nb < 4; ++nb) {
    const int d = nb * 16 + l15;
    #pragma unroll
    for (int r = 0; r < 4; ++r) {
      const int t = t0 + wv * 16 + quad * 4 + r;
      unsafeAtomicAdd(&out[((size_t)(blockIdx.z * T_ + t)) * (H_ * D_) + blockIdx.y * D_ + d],
                      oacc[nb][r]);
    }
  }
}

extern "C" void kernel_launch(void* const* d_in, const int* in_sizes, int n_in,
                              void* d_out, int out_size, void* d_ws, size_t ws_size,
                              hipStream_t stream) {
  const float* in = (const float*)d_in[0];
  const float* kw = (const float*)d_in[1];
  const float* kb = (const float*)d_in[2];
  const float* qw = (const float*)d_in[3];
  const float* qb = (const float*)d_in[4];
  const float* vw = (const float*)d_in[5];
  const float* vb = (const float*)d_in[6];
  float* out = (float*)d_out;

  // ws (bf16): in16 | qwt|kwt|vwt (H,D,E) | q16|k16 (B,H,T,D) | vt (B,H,D,T) | l fp32
  unsigned short* p = (unsigned short*)d_ws;
  const size_t inz = (size_t)B_ * T_ * E_;
  const size_t wz  = (size_t)H_ * D_ * E_;
  const size_t qz  = (size_t)B_ * H_ * T_ * D_;
  unsigned short* in16 = p;            p += inz;
  unsigned short* qwt  = p;            p += wz;
  unsigned short* kwt  = p;            p += wz;
  unsigned short* vwt  = p;            p += wz;
  unsigned short* q16  = p;            p += qz;
  unsigned short* k16  = p;            p += qz;
  unsigned short* vtb  = p;            p += qz;
  float* lbuf = (float*)p;

  hipMemsetAsync(lbuf, 0, (size_t)B_ * H_ * T_ * sizeof(float), stream);
  hipMemsetAsync(out, 0, (size_t)out_size * sizeof(float), stream);

  dim3 blk(256);
  inpack_kernel<<<dim3(inz / 2048), blk, 0, stream>>>(in, in16);
  wpack_kernel <<<dim3(E_ / 64, H_, 3), blk, 0, stream>>>(qw, kw, vw, qwt, kwt, vwt);
  proj_kernel  <<<dim3(T_ / 128, H_, B_), blk, 0, stream>>>(in16, qwt, kwt, vwt,
                                                            qb, kb, vb, q16, k16, vtb);
  stats_kernel <<<dim3(2 * NT_, H_, B_), blk, 0, stream>>>(q16, k16, lbuf);
  out_kernel   <<<dim3(2 * NT_, H_, B_), blk, 0, stream>>>(q16, k16, vtb, lbuf, out);
}

// Round 6
// 180.199 us; speedup vs baseline: 2.1138x; 1.1606x over previous
//
#include <hip/hip_runtime.h>
#include <hip/hip_bf16.h>
#include <math.h>

#define B_ 2
#define T_ 2048
#define E_ 1024
#define H_ 16
#define D_ 64
#define NT_ 32          // T/64 tiles
#define QSCALE 0.180336880f   // 0.125 * log2(e): folded into q so exp(S/8) = exp2(S')

typedef __attribute__((ext_vector_type(8))) short bf16x8;   // MFMA A/B frag (4 VGPRs)
typedef __attribute__((ext_vector_type(4))) float f32x4;    // MFMA C/D frag

#if __has_builtin(__builtin_amdgcn_exp2f)
#define EXP2(x) __builtin_amdgcn_exp2f(x)
#else
#define EXP2(x) exp2f(x)
#endif

__device__ __forceinline__ unsigned short f2bf(float x) {   // RNE fp32->bf16
  union { float f; unsigned u; } v; v.f = x;
  unsigned r = v.u + 0x7FFFu + ((v.u >> 16) & 1u);
  return (unsigned short)(r >> 16);
}
__device__ __forceinline__ unsigned pk2bf(float a, float b) {  // low=a, high=b (HW cvt_pk)
  __hip_bfloat162 h = __float22bfloat162_rn(make_float2(a, b));
  union { __hip_bfloat162 h; unsigned u; } c; c.h = h; return c.u;
}

// Async global->LDS: one wave-instr stages 8 rows x 64 bf16 (8 blocks of 16B),
// XOR-swizzled: LDS slot (row, bs) holds global block bs ^ (row&7).
__device__ __forceinline__ void dma8(const unsigned short* g, int gstride,
                                     unsigned short* l, int lane)
{
  const int r = lane >> 3, bg = (lane & 7) ^ (r & 7);
  __builtin_amdgcn_global_load_lds(
      (const __attribute__((address_space(1))) void*)(g + (size_t)r * gstride + bg * 8),
      (__attribute__((address_space(3))) void*)l, 16, 0, 0);
}
__device__ __forceinline__ bf16x8 frag(const unsigned short* tile, int row, int g) {
  return *(const bf16x8*)(tile + row * 64 + (((g ^ row) & 7) << 3));
}

// ---------------------------------------------------------------------------
// input pre-pack: (B,T,E) fp32 -> bf16. grid 2048 x 256.
// ---------------------------------------------------------------------------
__global__ __launch_bounds__(256) void inpack_kernel(const float* __restrict__ in,
                                                     unsigned short* __restrict__ o) {
  const size_t i = ((size_t)blockIdx.x * 256 + threadIdx.x) * 8;
  float4 f0 = *(const float4*)(in + i);
  float4 f1 = *(const float4*)(in + i + 4);
  unsigned u[4] = { pk2bf(f0.x, f0.y), pk2bf(f0.z, f0.w),
                    pk2bf(f1.x, f1.y), pk2bf(f1.z, f1.w) };
  *(bf16x8*)(o + i) = *(const bf16x8*)u;
}

// ---------------------------------------------------------------------------
// weight pack: (H,E,D) fp32 -> (H,D,E) bf16. grid (E/64, H, 3) x 256.
// ---------------------------------------------------------------------------
__global__ __launch_bounds__(256) void wpack_kernel(
    const float* __restrict__ qw, const float* __restrict__ kw, const float* __restrict__ vw,
    unsigned short* __restrict__ qwt, unsigned short* __restrict__ kwt,
    unsigned short* __restrict__ vwt)
{
  __shared__ float s[64][65];
  const int tid = threadIdx.x;
  const int e0 = blockIdx.x * 64, h = blockIdx.y, z = blockIdx.z;
  const float* w = (z == 0) ? qw : (z == 1) ? kw : vw;
  unsigned short* o = (z == 0) ? qwt : (z == 1) ? kwt : vwt;
  {
    const int r = tid >> 2;
    #pragma unroll
    for (int p = 0; p < 4; ++p) {
      const int c = (tid & 3) * 4 + p * 16;
      float4 f = *(const float4*)(w + ((size_t)(h * E_ + e0 + r)) * D_ + c);
      s[r][c] = f.x; s[r][c+1] = f.y; s[r][c+2] = f.z; s[r][c+3] = f.w;
    }
  }
  __syncthreads();
  {
    const int d = tid >> 2, ec = (tid & 3) * 16;
    unsigned short tmp[16];
    #pragma unroll
    for (int j = 0; j < 16; ++j) tmp[j] = f2bf(s[ec + j][d]);
    unsigned short* dst = o + ((size_t)(h * D_ + d)) * E_ + e0 + ec;
    *(bf16x8*)(dst)     = *(const bf16x8*)&tmp[0];
    *(bf16x8*)(dst + 8) = *(const bf16x8*)&tmp[8];
  }
}

// ---------------------------------------------------------------------------
// QKV projection (double-buffered global_load_lds). grid (T/128, H, B) = 512.
// q/k epilogues use swapped-operand MFMA (C col = t) for ushort4 stores;
// v written transposed [d][t]. q pre-scaled by QSCALE.
// ---------------------------------------------------------------------------
__global__ __launch_bounds__(256) void proj_kernel(
    const unsigned short* __restrict__ in16,
    const unsigned short* __restrict__ qwt, const unsigned short* __restrict__ kwt,
    const unsigned short* __restrict__ vwt,
    const float* __restrict__ qb, const float* __restrict__ kb, const float* __restrict__ vb,
    unsigned short* __restrict__ qo, unsigned short* __restrict__ ko,
    unsigned short* __restrict__ vt)
{
  __shared__ __align__(16) unsigned short in_s[2][128 * 64];   // 32 KB
  __shared__ __align__(16) unsigned short w_s[2][3][64 * 64];  // 48 KB
  const int tid = threadIdx.x;
  const int lane = tid & 63, wv = tid >> 6;
  const int l15 = lane & 15, quad = lane >> 4;
  const int t0 = blockIdx.x * 128, h = blockIdx.y, b = blockIdx.z;
  const int bh = b * H_ + h;
  const unsigned short* wts[3] = { qwt, kwt, vwt };

  f32x4 acc[3][2][4];
  #pragma unroll
  for (int x = 0; x < 3; ++x)
    #pragma unroll
    for (int s = 0; s < 2; ++s)
      #pragma unroll
      for (int nb = 0; nb < 4; ++nb) acc[x][s][nb] = (f32x4){0.f, 0.f, 0.f, 0.f};

#define PROJ_STAGE(e0_, bi_)                                                      \
  {                                                                               \
    const unsigned short* gin = in16 + ((size_t)(b * T_ + t0)) * E_ + (e0_);      \
    _Pragma("unroll")                                                             \
    for (int p = 0; p < 4; ++p) {                                                 \
      const int br = wv * 32 + p * 8;                                             \
      dma8(gin + (size_t)br * E_, E_, &in_s[bi_][br * 64], lane);                 \
    }                                                                             \
    _Pragma("unroll")                                                             \
    for (int j = 0; j < 6; ++j) {                                                 \
      const int idx = wv * 6 + j;                                                 \
      const int x = idx >> 3, br = (idx & 7) * 8;                                 \
      dma8(wts[x] + ((size_t)(h * D_ + br)) * E_ + (e0_), E_,                     \
           &w_s[bi_][x][br * 64], lane);                                          \
    }                                                                             \
  }

  PROJ_STAGE(0, 0);
  __syncthreads();
  for (int e = 0; e < 16; ++e) {
    const int bi = e & 1;
    if (e < 15) PROJ_STAGE((e + 1) * 64, bi ^ 1);
    const unsigned short* is = in_s[bi];
    #pragma unroll
    for (int kk = 0; kk < 2; ++kk) {
      const int g0 = kk * 4 + quad;
      bf16x8 a0 = frag(is, wv * 32 + l15, g0);
      bf16x8 a1 = frag(is, wv * 32 + 16 + l15, g0);
      #pragma unroll
      for (int x = 0; x < 3; ++x) {
        const unsigned short* ws = w_s[bi][x];
        #pragma unroll
        for (int nb = 0; nb < 4; ++nb) {
          bf16x8 bfr = frag(ws, nb * 16 + l15, g0);
          if (x < 2) {   // q,k: A=w (m=d), B=in (n=t) -> C col=t, rows=d
            acc[x][0][nb] = __builtin_amdgcn_mfma_f32_16x16x32_bf16(bfr, a0, acc[x][0][nb], 0, 0, 0);
            acc[x][1][nb] = __builtin_amdgcn_mfma_f32_16x16x32_bf16(bfr, a1, acc[x][1][nb], 0, 0, 0);
          } else {       // v: A=in (m=t), B=w (n=d) -> C col=d, rows=t
            acc[x][0][nb] = __builtin_amdgcn_mfma_f32_16x16x32_bf16(a0, bfr, acc[x][0][nb], 0, 0, 0);
            acc[x][1][nb] = __builtin_amdgcn_mfma_f32_16x16x32_bf16(a1, bfr, acc[x][1][nb], 0, 0, 0);
          }
        }
      }
    }
    __syncthreads();
  }
#undef PROJ_STAGE

  const size_t obase = (size_t)bh * T_;
  // q (scaled) and k: lane t fixed, 4 consecutive d -> ushort4 stores
  #pragma unroll
  for (int x = 0; x < 2; ++x) {
    const float scl = (x == 0) ? QSCALE : 1.0f;
    const float* bias = (x == 0) ? qb : kb;
    unsigned short* outp = (x == 0) ? qo : ko;
    #pragma unroll
    for (int nb = 0; nb < 4; ++nb) {
      float bias4[4];
      *(float4*)bias4 = *(const float4*)&bias[h * D_ + nb * 16 + quad * 4];
      #pragma unroll
      for (int s = 0; s < 2; ++s) {
        const int t = t0 + wv * 32 + s * 16 + l15;
        unsigned short pk[4];
        #pragma unroll
        for (int r = 0; r < 4; ++r) pk[r] = f2bf((acc[x][s][nb][r] + bias4[r]) * scl);
        *(ushort4*)(outp + (obase + t) * D_ + nb * 16 + quad * 4) = *(const ushort4*)pk;
      }
    }
  }
  // v: transposed [d][t] — lane d fixed, 4 consecutive t -> ushort4 stores
  #pragma unroll
  for (int nb = 0; nb < 4; ++nb) {
    const int d = nb * 16 + l15;
    const float bvv = vb[h * D_ + d];
    #pragma unroll
    for (int s = 0; s < 2; ++s) {
      const int t = t0 + wv * 32 + s * 16 + quad * 4;
      unsigned short pk[4];
      #pragma unroll
      for (int r = 0; r < 4; ++r) pk[r] = f2bf(acc[2][s][nb][r] + bvv);
      *(ushort4*)(vt + ((size_t)(bh * D_ + d)) * T_ + t) = *(const ushort4*)pk;
    }
  }
}

// ---------------------------------------------------------------------------
// Column softmax: lg[s] = -log2( sum_t exp2(S'[t,s]) ). grid (H, B, NT) —
// z-major gives each CU a balanced spread of s-tiles; sa=0 (heaviest) first.
// K B-frags reg-resident (one-time), Q dbuf via dma8. 17.5 KB LDS.
// ---------------------------------------------------------------------------
__global__ __launch_bounds__(256, 6) void stats_kernel(
    const unsigned short* __restrict__ q, const unsigned short* __restrict__ k,
    float* __restrict__ lg)
{
  __shared__ __align__(16) unsigned short q_s[2][64 * 64];   // 16 KB
  __shared__ float red[4][64];
  const int tid = threadIdx.x;
  const int lane = tid & 63, wv = tid >> 6;
  const int l15 = lane & 15, quad = lane >> 4;
  const int h = blockIdx.x, b = blockIdx.y, sa = blockIdx.z;
  const int bh = b * H_ + h;
  const int s0 = sa * 64;
  const unsigned short* qbase = q + (size_t)bh * T_ * 64;

  bf16x8 kf[4][2];                               // reg-resident K B-frags (one-time)
  #pragma unroll
  for (int nb = 0; nb < 4; ++nb)
    #pragma unroll
    for (int kk = 0; kk < 2; ++kk)
      kf[nb][kk] = *(const bf16x8*)(k + ((size_t)(bh * T_ + s0 + nb * 16 + l15)) * 64
                                      + kk * 32 + quad * 8);

  #pragma unroll
  for (int pp = 0; pp < 2; ++pp) {
    const int br = wv * 16 + pp * 8;
    dma8(qbase + (size_t)(sa * 64 + br) * 64, 64, &q_s[0][br * 64], lane);
  }
  __syncthreads();

  float lsum[4] = {0.f, 0.f, 0.f, 0.f};

  for (int tt = sa, i = 0; tt < NT_; ++tt, ++i) {
    const int bi = i & 1;
    if (tt + 1 < NT_) {
      #pragma unroll
      for (int pp = 0; pp < 2; ++pp) {
        const int br = wv * 16 + pp * 8;
        dma8(qbase + (size_t)((tt + 1) * 64 + br) * 64, 64, &q_s[bi ^ 1][br * 64], lane);
      }
    }
    bf16x8 a0 = frag(q_s[bi], wv * 16 + l15, quad);
    bf16x8 a1 = frag(q_s[bi], wv * 16 + l15, 4 + quad);
    f32x4 sacc[4];
    #pragma unroll
    for (int nb = 0; nb < 4; ++nb) sacc[nb] = (f32x4){0.f, 0.f, 0.f, 0.f};
    #pragma unroll
    for (int nb = 0; nb < 4; ++nb) {
      sacc[nb] = __builtin_amdgcn_mfma_f32_16x16x32_bf16(a0, kf[nb][0], sacc[nb], 0, 0, 0);
      sacc[nb] = __builtin_amdgcn_mfma_f32_16x16x32_bf16(a1, kf[nb][1], sacc[nb], 0, 0, 0);
    }
    if (tt == sa) {                              // diagonal tile: causal mask
      const int tbase = tt * 64 + wv * 16 + quad * 4;
      #pragma unroll
      for (int nb = 0; nb < 4; ++nb) {
        const int s = s0 + nb * 16 + l15;
        #pragma unroll
        for (int r = 0; r < 4; ++r)
          lsum[nb] += (tbase + r >= s) ? EXP2(sacc[nb][r]) : 0.f;
      }
    } else {
      #pragma unroll
      for (int nb = 0; nb < 4; ++nb)
        #pragma unroll
        for (int r = 0; r < 4; ++r) lsum[nb] += EXP2(sacc[nb][r]);
    }
    __syncthreads();
  }
  #pragma unroll
  for (int nb = 0; nb < 4; ++nb) {
    lsum[nb] += __shfl_xor(lsum[nb], 16);
    lsum[nb] += __shfl_xor(lsum[nb], 32);
  }
  if (lane < 16) {
    #pragma unroll
    for (int nb = 0; nb < 4; ++nb) red[wv][nb * 16 + lane] = lsum[nb];
  }
  __syncthreads();
  if (tid < 64) {
    const float L = red[0][tid] + red[1][tid] + red[2][tid] + red[3][tid];
    lg[(size_t)bh * T_ + s0 + tid] = -__log2f(L);
  }
}

// ---------------------------------------------------------------------------
// Output. grid (H, B, NT), jt = 31-z (heavy-first, balanced per CU).
// 25.8 KB LDS -> 6 blocks/CU capacity (4 assigned, all resident).
// Per unit: single-slot K/Vt staging (2 barriers), S^T = K.Q^T with sacc
// initialized to lg[s] (normalization fused into exp2), U -> wave-private
// LDS, O^T = Vt.U^T (A=Vt, B=U) -> float4 coalesced stores.
// ---------------------------------------------------------------------------
__global__ __launch_bounds__(256, 6) void out_kernel(
    const unsigned short* __restrict__ q, const unsigned short* __restrict__ k,
    const unsigned short* __restrict__ vt, const float* __restrict__ lg,
    float* __restrict__ out)
{
  __shared__ __align__(16) unsigned short k_s[64 * 64];       // 8 KB
  __shared__ __align__(16) unsigned short vt_s[64 * 64];      // 8 KB
  __shared__ __align__(16) unsigned short u_s[4][16][72];     // 9.2 KB wave-private
  __shared__ float lg_sh[64];
  const int tid = threadIdx.x;
  const int lane = tid & 63, wv = tid >> 6;
  const int l15 = lane & 15, quad = lane >> 4;
  const int h = blockIdx.x, b = blockIdx.y, jt = 31 - blockIdx.z;
  const int bh = b * H_ + h;
  const int t0 = jt * 64;
  const unsigned short* kbase = k + (size_t)bh * T_ * 64;
  const unsigned short* vbase = vt + (size_t)bh * D_ * T_;
  const float* lgbase = lg + (size_t)bh * T_;

  // one-time Q B-frags (direct global)
  const unsigned short* qrow = q + (size_t)(bh * T_ + t0 + wv * 16 + l15) * 64;
  bf16x8 qf0 = *(const bf16x8*)(qrow + quad * 8);
  bf16x8 qf1 = *(const bf16x8*)(qrow + 32 + quad * 8);

  f32x4 oacc[4];
  #pragma unroll
  for (int nb = 0; nb < 4; ++nb) oacc[nb] = (f32x4){0.f, 0.f, 0.f, 0.f};

  unsigned short* urow = &u_s[wv][l15][0];
  const int tcol = t0 + wv * 16 + l15;

  for (int st = 0; st <= jt; ++st) {
    const int s0 = st * 64;
    __syncthreads();                             // all waves done with k_s/vt_s/lg_sh
    #pragma unroll
    for (int pp = 0; pp < 2; ++pp) {
      const int br = wv * 16 + pp * 8;
      dma8(kbase + (size_t)(s0 + br) * 64, 64, &k_s[br * 64], lane);
      dma8(vbase + (size_t)br * T_ + s0, T_, &vt_s[br * 64], lane);
    }
    if (tid < 64) lg_sh[tid] = lgbase[s0 + tid];
    __syncthreads();                             // drain: tiles + lg landed
    // S^T tile: A = K rows (s), B = Q (reg); C init = lg[s] fuses 1/l
    f32x4 sacc[4];
    #pragma unroll
    for (int mb = 0; mb < 4; ++mb) {
      float lg4[4];
      *(float4*)lg4 = *(const float4*)&lg_sh[mb * 16 + quad * 4];
      sacc[mb] = (f32x4){lg4[0], lg4[1], lg4[2], lg4[3]};
    }
    #pragma unroll
    for (int mb = 0; mb < 4; ++mb) {
      bf16x8 ka0 = frag(k_s, mb * 16 + l15, quad);
      bf16x8 ka1 = frag(k_s, mb * 16 + l15, 4 + quad);
      sacc[mb] = __builtin_amdgcn_mfma_f32_16x16x32_bf16(ka0, qf0, sacc[mb], 0, 0, 0);
      sacc[mb] = __builtin_amdgcn_mfma_f32_16x16x32_bf16(ka1, qf1, sacc[mb], 0, 0, 0);
    }
    // U = exp2(S' + lg[s]) masked on diagonal; write wave-private row
    if (st == jt) {
      #pragma unroll
      for (int mb = 0; mb < 4; ++mb) {
        const int sbase = s0 + mb * 16 + quad * 4;
        float uu[4] = { EXP2(sacc[mb][0]), EXP2(sacc[mb][1]),
                        EXP2(sacc[mb][2]), EXP2(sacc[mb][3]) };
        #pragma unroll
        for (int r = 0; r < 4; ++r) if (tcol < sbase + r) uu[r] = 0.f;
        *(uint2*)(urow + mb * 16 + quad * 4) =
            make_uint2(pk2bf(uu[0], uu[1]), pk2bf(uu[2], uu[3]));
      }
    } else {
      #pragma unroll
      for (int mb = 0; mb < 4; ++mb) {
        float uu[4] = { EXP2(sacc[mb][0]), EXP2(sacc[mb][1]),
                        EXP2(sacc[mb][2]), EXP2(sacc[mb][3]) };
        *(uint2*)(urow + mb * 16 + quad * 4) =
            make_uint2(pk2bf(uu[0], uu[1]), pk2bf(uu[2], uu[3]));
      }
    }
    // O^T += Vt . U^T : A = Vt rows (d), B = own U row (n=t) — same-wave LDS dep
    #pragma unroll
    for (int kk = 0; kk < 2; ++kk) {
      bf16x8 ua = *(const bf16x8*)(urow + kk * 32 + quad * 8);
      #pragma unroll
      for (int nb = 0; nb < 4; ++nb)
        oacc[nb] = __builtin_amdgcn_mfma_f32_16x16x32_bf16(
            frag(vt_s, nb * 16 + l15, kk * 4 + quad), ua, oacc[nb], 0, 0, 0);
    }
  }
  // O^T C-layout: lane t = t0+wv*16+l15, rows = d -> float4 coalesced stores
  float* orow = out + ((size_t)(b * T_ + t0 + wv * 16 + l15)) * (H_ * D_) + h * D_;
  #pragma unroll
  for (int nb = 0; nb < 4; ++nb) {
    float o4[4] = { oacc[nb][0], oacc[nb][1], oacc[nb][2], oacc[nb][3] };
    *(float4*)(orow + nb * 16 + quad * 4) = *(const float4*)o4;
  }
}

extern "C" void kernel_launch(void* const* d_in, const int* in_sizes, int n_in,
                              void* d_out, int out_size, void* d_ws, size_t ws_size,
                              hipStream_t stream) {
  const float* in = (const float*)d_in[0];
  const float* kw = (const float*)d_in[1];
  const float* kb = (const float*)d_in[2];
  const float* qw = (const float*)d_in[3];
  const float* qb = (const float*)d_in[4];
  const float* vw = (const float*)d_in[5];
  const float* vb = (const float*)d_in[6];
  float* out = (float*)d_out;

  // ws (bf16): in16 | qwt|kwt|vwt (H,D,E) | q16|k16 (B,H,T,D) | vt (B,H,D,T) | lg fp32
  unsigned short* p = (unsigned short*)d_ws;
  const size_t inz = (size_t)B_ * T_ * E_;
  const size_t wz  = (size_t)H_ * D_ * E_;
  const size_t qz  = (size_t)B_ * H_ * T_ * D_;
  unsigned short* in16 = p;            p += inz;
  unsigned short* qwt  = p;            p += wz;
  unsigned short* kwt  = p;            p += wz;
  unsigned short* vwt  = p;            p += wz;
  unsigned short* q16  = p;            p += qz;
  unsigned short* k16  = p;            p += qz;
  unsigned short* vtb  = p;            p += qz;
  float* lgbuf = (float*)p;

  dim3 blk(256);
  inpack_kernel<<<dim3(inz / 2048), blk, 0, stream>>>(in, in16);
  wpack_kernel <<<dim3(E_ / 64, H_, 3), blk, 0, stream>>>(qw, kw, vw, qwt, kwt, vwt);
  proj_kernel  <<<dim3(T_ / 128, H_, B_), blk, 0, stream>>>(in16, qwt, kwt, vwt,
                                                            qb, kb, vb, q16, k16, vtb);
  stats_kernel <<<dim3(H_, B_, NT_), blk, 0, stream>>>(q16, k16, lgbuf);
  out_kernel   <<<dim3(H_, B_, NT_), blk, 0, stream>>>(q16, k16, vtb, lgbuf, out);
}